// Round 2
// baseline (58.899 us; speedup 1.0000x reference)
//
#include <hip/hip_runtime.h>
#include <hip/hip_bf16.h>

#define NB 16
#define NT 128
#define NR 8192
#define NC 91
#define IOU_TH 0.7f

__device__ __forceinline__ float smooth_l1(float x) {
    float ax = fabsf(x);
    return ax < 1.0f ? 0.5f * x * x : ax - 0.5f;
}

// acc layout (floats): [0]=count, [1]=sum nll, [2]=sum reg, [3]=sum correct
__global__ __launch_bounds__(256) void frcnn_main(
    const float* __restrict__ nms_reg,
    const float* __restrict__ rcnn_reg,
    const float* __restrict__ rcnn_cls,
    const float* __restrict__ bboxes,
    const int* __restrict__ classes,
    const int* __restrict__ reduction,
    float* __restrict__ acc)
{
    __shared__ float sbox[NT][4];
    __shared__ int   scls[NT];
    __shared__ float sred[4][4];

    const int b = blockIdx.x >> 5;                       // 32 blocks per batch
    const int r = ((blockIdx.x & 31) << 8) + threadIdx.x;

    if (threadIdx.x < NT) {
        const float4 p = *(const float4*)(bboxes + ((size_t)b * NT + threadIdx.x) * 4);
        sbox[threadIdx.x][0] = p.x;
        sbox[threadIdx.x][1] = p.y;
        sbox[threadIdx.x][2] = p.z;
        sbox[threadIdx.x][3] = p.w;
        scls[threadIdx.x] = classes[b * NT + threadIdx.x];
    }
    __syncthreads();

    const size_t pidx = (size_t)b * NR + r;

    // proposal box
    const float4 pr = *(const float4*)(nms_reg + pidx * 4);
    const float a0 = pr.x, a1 = pr.y, a2 = pr.z, a3 = pr.w;
    const float area_a = (a2 - a0) * (a3 - a1);

    // IoU max + first-occurrence argmax over targets (matches jnp.argmax)
    float best = -INFINITY;
    int bidx = 0;
    #pragma unroll 4
    for (int t = 0; t < NT; ++t) {
        const float b0 = sbox[t][0], b1 = sbox[t][1], b2v = sbox[t][2], b3 = sbox[t][3];
        const float it = fmaxf(a0, b0);
        const float il = fmaxf(a1, b1);
        const float ib = fminf(a2, b2v);
        const float ir = fminf(a3, b3);
        const float inter = fmaxf(ib - it, 0.f) * fmaxf(ir - il, 0.f);
        const float area_b = (b2v - b0) * (b3 - b1);
        const float iou = inter / (area_a + area_b - inter);
        if (iou > best) { best = iou; bidx = t; }
    }

    float cnt = 0.f, nll = 0.f, reg = 0.f, corr = 0.f;
    if (best > IOU_TH) {
        cnt = 1.f;
        const int cls = scls[bidx];

        // --- cross-entropy + accuracy over C=91 logits ---
        const float* lg = rcnn_cls + pidx * NC;
        float m = -INFINITY; int am = 0;
        for (int c = 0; c < NC; ++c) {
            const float v = lg[c];
            if (v > m) { m = v; am = c; }     // first-occurrence argmax
        }
        float s = 0.f;
        for (int c = 0; c < NC; ++c) {
            s += __expf(lg[c] - m);
        }
        const float lc = lg[cls];
        nll = m + logf(s) - lc;
        corr = (am == cls) ? 1.f : 0.f;

        // --- smooth-L1 regression loss ---
        const int rv = *reduction;
        float redv;
        if (rv >= 1 && rv <= 65536) redv = (float)rv;      // int scalar (expected: 16)
        else redv = __int_as_float(rv);                    // defensive: float32-encoded scalar

        float bb[4], rd[4];
        #pragma unroll
        for (int k = 0; k < 4; ++k) {
            bb[k] = sbox[bidx][k];
            rd[k] = rintf(bb[k] / redv) * redv;            // jnp.round = half-to-even = rintf
        }
        float hgt = rd[2] - rd[0]; if (hgt == 0.f) hgt = 1.f;
        float wid = rd[3] - rd[1]; if (wid == 0.f) wid = 1.f;

        const float4 rr = *(const float4*)(rcnn_reg + pidx * 4);
        const float t0 = rr.x - (bb[0] - rd[0]) / hgt;
        const float t1 = rr.y - (bb[1] - rd[1]) / wid;
        const float t2 = rr.z - (bb[2] - rd[2]) / hgt;
        const float t3 = rr.w - (bb[3] - rd[3]) / wid;
        reg = smooth_l1(t0) + smooth_l1(t1) + smooth_l1(t2) + smooth_l1(t3);
    }

    // wave(64) reduction then cross-wave via LDS
    #pragma unroll
    for (int off = 32; off > 0; off >>= 1) {
        cnt  += __shfl_down(cnt,  off);
        nll  += __shfl_down(nll,  off);
        reg  += __shfl_down(reg,  off);
        corr += __shfl_down(corr, off);
    }
    const int lane = threadIdx.x & 63;
    const int w    = threadIdx.x >> 6;
    if (lane == 0) { sred[w][0] = cnt; sred[w][1] = nll; sred[w][2] = reg; sred[w][3] = corr; }
    __syncthreads();
    if (threadIdx.x == 0) {
        float c = 0.f, n = 0.f, g = 0.f, a = 0.f;
        #pragma unroll
        for (int i = 0; i < 4; ++i) { c += sred[i][0]; n += sred[i][1]; g += sred[i][2]; a += sred[i][3]; }
        atomicAdd(&acc[0], c);
        atomicAdd(&acc[1], n);
        atomicAdd(&acc[2], g);
        atomicAdd(&acc[3], a);
    }
}

__global__ void frcnn_final(const float* __restrict__ acc, float* __restrict__ out)
{
    if (threadIdx.x == 0 && blockIdx.x == 0) {
        const float count = acc[0];
        const float pos   = (count > 0.f) ? 1.f : 0.f;
        const float denom = fmaxf(count, 1.f);
        out[0] = acc[1] / denom * pos;   // cls_loss
        out[1] = acc[2] / denom * pos;   // reg_loss
        out[2] = acc[3] / denom * pos;   // accuracy
    }
}

extern "C" void kernel_launch(void* const* d_in, const int* in_sizes, int n_in,
                              void* d_out, int out_size, void* d_ws, size_t ws_size,
                              hipStream_t stream) {
    // setup_inputs order: nms_reg, nms_cls(unused), rcnn_reg, rcnn_cls, bboxes, classes, reduction
    const float* nms_reg  = (const float*)d_in[0];
    const float* rcnn_reg = (const float*)d_in[2];
    const float* rcnn_cls = (const float*)d_in[3];
    const float* bboxes   = (const float*)d_in[4];
    const int*   classes  = (const int*)d_in[5];
    const int*   red      = (const int*)d_in[6];

    float* acc = (float*)d_ws;
    hipMemsetAsync(acc, 0, 4 * sizeof(float), stream);

    const int blocks = NB * (NR / 256);   // 512
    frcnn_main<<<blocks, 256, 0, stream>>>(nms_reg, rcnn_reg, rcnn_cls, bboxes, classes, red, acc);
    frcnn_final<<<1, 64, 0, stream>>>(acc, (float*)d_out);
}

// Round 3
// 36.848 us; speedup vs baseline: 1.5984x; 1.5984x over previous
//
#include <hip/hip_runtime.h>
#include <hip/hip_bf16.h>

#define NB 16
#define NT 128
#define NR 8192
#define NC 91
#define IOU_TH 0.7f

#define BLOCKS_MAIN (NB * NR / 16)   // 16 proposals (groups) per block -> 8192

__device__ __forceinline__ float smooth_l1(float x) {
    float ax = fabsf(x);
    return ax < 1.0f ? 0.5f * x * x : ax - 0.5f;
}

// Each 16-lane group owns one proposal. Block = 256 threads = 16 proposals.
// Per-block partial sums {count, nll, reg, correct} written to part[blockIdx].
__global__ __launch_bounds__(256) void frcnn_main(
    const float* __restrict__ nms_reg,
    const float* __restrict__ rcnn_reg,
    const float* __restrict__ rcnn_cls,
    const float* __restrict__ bboxes,
    const int* __restrict__ classes,
    const int* __restrict__ reduction,
    float4* __restrict__ part)
{
    __shared__ float4 sbox[NT];
    __shared__ int    scls[NT];
    __shared__ float4 sred[4];

    const int b    = blockIdx.x >> 9;          // 512 blocks per batch
    const int tile = blockIdx.x & 511;
    const int grp  = threadIdx.x >> 4;         // 0..15
    const int l    = threadIdx.x & 15;
    const int r    = tile * 16 + grp;

    if (threadIdx.x < NT) {
        sbox[threadIdx.x] = ((const float4*)bboxes)[b * NT + threadIdx.x];
        scls[threadIdx.x] = classes[b * NT + threadIdx.x];
    }
    __syncthreads();

    const size_t pidx = (size_t)b * NR + r;

    // proposal box (group-uniform load, one cache line per group)
    const float4 pr = ((const float4*)nms_reg)[pidx];
    const float a0 = pr.x, a1 = pr.y, a2 = pr.z, a3 = pr.w;
    const float area_a = (a2 - a0) * (a3 - a1);

    // IoU max + first-occurrence argmax: lane l covers targets l, l+16, ..., l+112
    float best = -INFINITY;
    int   bidx = 0;
    #pragma unroll
    for (int j = 0; j < 8; ++j) {
        const int t = l + 16 * j;
        const float4 tb = sbox[t];
        const float it = fmaxf(a0, tb.x);
        const float il = fmaxf(a1, tb.y);
        const float ib = fminf(a2, tb.z);
        const float ir = fminf(a3, tb.w);
        const float inter = fmaxf(ib - it, 0.f) * fmaxf(ir - il, 0.f);
        const float area_b = (tb.z - tb.x) * (tb.w - tb.y);
        const float iou = inter / (area_a + area_b - inter);
        if (iou > best) { best = iou; bidx = t; }   // in-lane ascending t => first occurrence
    }
    #pragma unroll
    for (int m = 8; m; m >>= 1) {
        const float oi = __shfl_xor(best, m, 16);
        const int   ox = __shfl_xor(bidx, m, 16);
        if (oi > best || (oi == best && ox < bidx)) { best = oi; bidx = ox; }
    }

    float cnt = 0.f, nll = 0.f, reg = 0.f, corr = 0.f;
    if (best > IOU_TH) {                       // group-uniform branch
        const int cls = scls[bidx];

        // --- cross-entropy + accuracy: lane l owns classes l+16j, coalesced ---
        const float* lg = rcnn_cls + pidx * NC;
        float v[6];
        float m = -INFINITY; int am = NC;
        #pragma unroll
        for (int j = 0; j < 6; ++j) {
            const int c = l + 16 * j;
            v[j] = (c < NC) ? lg[c] : -INFINITY;
            if (v[j] > m) { m = v[j]; am = c; } // in-lane ascending c => first occurrence
        }
        #pragma unroll
        for (int mk = 8; mk; mk >>= 1) {
            const float om = __shfl_xor(m, mk, 16);
            const int   oa = __shfl_xor(am, mk, 16);
            if (om > m || (om == m && oa < am)) { m = om; am = oa; }
        }
        float s = 0.f;
        #pragma unroll
        for (int j = 0; j < 6; ++j) {
            if (l + 16 * j < NC) s += __expf(v[j] - m);
        }
        #pragma unroll
        for (int mk = 8; mk; mk >>= 1) s += __shfl_xor(s, mk, 16);

        if (l == 0) {
            const float lc = lg[cls];
            cnt  = 1.f;
            nll  = m + logf(s) - lc;
            corr = (am == cls) ? 1.f : 0.f;

            // --- smooth-L1 regression loss ---
            const int rv = *reduction;
            float redv;
            if (rv >= 1 && rv <= 65536) redv = (float)rv;   // int scalar (expected 16)
            else redv = __int_as_float(rv);                 // defensive: f32-encoded

            const float4 bb = sbox[bidx];
            const float rd0 = rintf(bb.x / redv) * redv;
            const float rd1 = rintf(bb.y / redv) * redv;
            const float rd2 = rintf(bb.z / redv) * redv;
            const float rd3 = rintf(bb.w / redv) * redv;
            float hgt = rd2 - rd0; if (hgt == 0.f) hgt = 1.f;
            float wid = rd3 - rd1; if (wid == 0.f) wid = 1.f;

            const float4 rr = ((const float4*)rcnn_reg)[pidx];
            reg = smooth_l1(rr.x - (bb.x - rd0) / hgt)
                + smooth_l1(rr.y - (bb.y - rd1) / wid)
                + smooth_l1(rr.z - (bb.z - rd2) / hgt)
                + smooth_l1(rr.w - (bb.w - rd3) / wid);
        }
    }
    // non-lane0 threads contribute zeros

    // wave(64) reduction then cross-wave via LDS; no atomics
    #pragma unroll
    for (int off = 32; off > 0; off >>= 1) {
        cnt  += __shfl_down(cnt,  off);
        nll  += __shfl_down(nll,  off);
        reg  += __shfl_down(reg,  off);
        corr += __shfl_down(corr, off);
    }
    const int lane = threadIdx.x & 63;
    const int w    = threadIdx.x >> 6;
    if (lane == 0) sred[w] = make_float4(cnt, nll, reg, corr);
    __syncthreads();
    if (threadIdx.x == 0) {
        float4 t = make_float4(0.f, 0.f, 0.f, 0.f);
        #pragma unroll
        for (int i = 0; i < 4; ++i) {
            t.x += sred[i].x; t.y += sred[i].y; t.z += sred[i].z; t.w += sred[i].w;
        }
        part[blockIdx.x] = t;
    }
}

// Single-block tree reduce of the 8192 float4 partials + finalize.
__global__ __launch_bounds__(1024) void frcnn_reduce(
    const float4* __restrict__ part, float* __restrict__ out)
{
    __shared__ float4 sw[16];
    float4 s = make_float4(0.f, 0.f, 0.f, 0.f);
    for (int i = threadIdx.x; i < BLOCKS_MAIN; i += 1024) {
        const float4 p = part[i];
        s.x += p.x; s.y += p.y; s.z += p.z; s.w += p.w;
    }
    #pragma unroll
    for (int off = 32; off > 0; off >>= 1) {
        s.x += __shfl_down(s.x, off);
        s.y += __shfl_down(s.y, off);
        s.z += __shfl_down(s.z, off);
        s.w += __shfl_down(s.w, off);
    }
    const int lane = threadIdx.x & 63;
    const int w    = threadIdx.x >> 6;
    if (lane == 0) sw[w] = s;
    __syncthreads();
    if (threadIdx.x == 0) {
        float4 t = make_float4(0.f, 0.f, 0.f, 0.f);
        #pragma unroll
        for (int i = 0; i < 16; ++i) {
            t.x += sw[i].x; t.y += sw[i].y; t.z += sw[i].z; t.w += sw[i].w;
        }
        const float pos   = (t.x > 0.f) ? 1.f : 0.f;
        const float denom = fmaxf(t.x, 1.f);
        out[0] = t.y / denom * pos;   // cls_loss
        out[1] = t.z / denom * pos;   // reg_loss
        out[2] = t.w / denom * pos;   // accuracy
    }
}

extern "C" void kernel_launch(void* const* d_in, const int* in_sizes, int n_in,
                              void* d_out, int out_size, void* d_ws, size_t ws_size,
                              hipStream_t stream) {
    // setup_inputs order: nms_reg, nms_cls(unused), rcnn_reg, rcnn_cls, bboxes, classes, reduction
    const float* nms_reg  = (const float*)d_in[0];
    const float* rcnn_reg = (const float*)d_in[2];
    const float* rcnn_cls = (const float*)d_in[3];
    const float* bboxes   = (const float*)d_in[4];
    const int*   classes  = (const int*)d_in[5];
    const int*   red      = (const int*)d_in[6];

    float4* part = (float4*)d_ws;   // BLOCKS_MAIN * 16 B = 128 KiB, fully rewritten each launch

    frcnn_main<<<BLOCKS_MAIN, 256, 0, stream>>>(nms_reg, rcnn_reg, rcnn_cls, bboxes,
                                                classes, red, part);
    frcnn_reduce<<<1, 1024, 0, stream>>>(part, (float*)d_out);
}